// Round 7
// baseline (240.396 us; speedup 1.0000x reference)
//
#include <hip/hip_runtime.h>

// Problem dims (fixed by setup_inputs)
constexpr int Bc = 4, Cc = 128, Hc = 192, Wc = 192;
constexpr int HI = 96, WI = 96;       // half-res inputs
constexpr int NB = 64;                // n_bins
constexpr int NA = 16;                // n_att
constexpr float SCL = 95.0f / 191.0f; // align_corners scale (96->192)

typedef __attribute__((ext_vector_type(8))) short bf16x8;
typedef __attribute__((ext_vector_type(4))) float f32x4;

__device__ __forceinline__ unsigned short f2bf(float f) {
  unsigned u = __builtin_bit_cast(unsigned, f);
  unsigned r = (u + 0x7FFFu + ((u >> 16) & 1u)) >> 16;   // RNE
  return (unsigned short)r;
}
__device__ __forceinline__ float bf2f(unsigned short h) {
  unsigned u = ((unsigned)h) << 16;
  return __builtin_bit_cast(float, u);
}
__device__ __forceinline__ float rcp_fast(float r) {
#if defined(__has_builtin)
#if __has_builtin(__builtin_amdgcn_rcpf)
  return __builtin_amdgcn_rcpf(r);
#else
  return 1.0f / r;
#endif
#else
  return 1.0f / r;
#endif
}

// ---------------------------------------------------------------------------
// Prep: w1 (128x128 f32) -> bf16; even rows of w2 (16x128) -> bf16. Into ws.
// ---------------------------------------------------------------------------
__global__ __launch_bounds__(256) void k_prep(
    const float* __restrict__ w1, const float* __restrict__ w2,
    unsigned short* __restrict__ w1bf, unsigned short* __restrict__ w2bf)
{
  const int t = blockIdx.x * 256 + threadIdx.x;   // 0..18431
  if (t < 16384) {
    w1bf[t] = f2bf(w1[t]);
  } else {
    const int u = t - 16384;                      // 0..2047
    const int j = u >> 7, c = u & 127;
    w2bf[u] = f2bf(w2[(2 * j) * 128 + c]);        // even rows only
  }
}

// ---------------------------------------------------------------------------
// K1 (MFMA): h = x + bilinear(pbe); a1 = relu(h@w1^T+b1);
//            att16 = bf16(relu(a1@w2e^T+b2e)+1e-3)  -> ws [b][y][x][j]
// One block per (b, y, 64-px x-tile). 256 threads = 4 waves.
// ALL 68 global loads (36 pbe + 32 x) are issued into explicit register
// arrays BEFORE any consumption -> single HBM latency round per wave
// (previous versions let the scheduler chunk loads at ~8 in flight).
// ---------------------------------------------------------------------------
__global__ __launch_bounds__(256, 4) void k_att(
    const float* __restrict__ x, const float* __restrict__ pbe,
    const unsigned short* __restrict__ w1bf, const float* __restrict__ b1,
    const unsigned short* __restrict__ w2bf, const float* __restrict__ b2,
    unsigned short* __restrict__ att16)
{
  constexpr int PH = 136;   // a1_s pitch (bf16)
  constexpr int RP = 37;    // row_s pitch (f32), odd
  __shared__ __align__(16) unsigned char smem[128 * RP * 4];    // 18944 B
  float*          row_s = (float*)smem;                         // [128][37]
  unsigned short* a1_s  = (unsigned short*)smem;                // [64][136]

  const int tid = threadIdx.x;
  const int xg0 = blockIdx.x * 64;
  const int y = blockIdx.y;
  const int b = blockIdx.z;

  const float ysf = y * SCL;
  const int y0 = (int)ysf;
  const int y1 = min(y0 + 1, HI - 1);
  const float wy = ysf - (float)y0;
  const int xi0 = (int)(xg0 * SCL);

  const int lane = tid & 63;
  const int wv = tid >> 6;        // wave id 0..3
  const int ln = lane & 15;
  const int qd = lane >> 4;
  const int m0 = wv * 16;

  const int px = m0 + ln;
  const int xg = xg0 + px;
  const float xsf = (float)xg * SCL;
  const int x0i = (int)xsf;
  const float wx = xsf - (float)x0i;
  const int xl = x0i - xi0;             // 0..32, xl+1 <= 33

  // ---- batched load round 1: 36 pbe values into registers (no consumption)
  float tops[18], bots[18];
  #pragma unroll
  for (int i = 0; i < 18; ++i) {
    const int f = tid + 256 * i;        // 0..4607
    const int c = f / 36;
    const int xi = f - c * 36;
    const int xgl = min(xi0 + xi, WI - 1);
    const float* p = pbe + (size_t)(b * Cc + c) * (HI * WI);
    tops[i] = p[y0 * WI + xgl];
    bots[i] = p[y1 * WI + xgl];
  }
  // ---- batched load round 1 (cont.): 32 x values into registers
  float xr[32];
  #pragma unroll
  for (int kt = 0; kt < 4; ++kt) {
    #pragma unroll
    for (int j = 0; j < 8; ++j) {
      const int c = kt * 32 + qd * 8 + j;
      xr[kt * 8 + j] = x[((size_t)(b * Cc + c) * Hc + y) * Wc + xg];
    }
  }

  // ---- consume: row_s[c][xi] = y-interp (waits only on tops/bots)
  #pragma unroll
  for (int i = 0; i < 18; ++i) {
    const int f = tid + 256 * i;
    const int c = f / 36;
    const int xi = f - c * 36;
    row_s[c * RP + xi] = tops[i] + wy * (bots[i] - tops[i]);
  }
  __syncthreads();

  // ---- build A-fragments in registers from xr + row_s
  bf16x8 af[4];
  #pragma unroll
  for (int kt = 0; kt < 4; ++kt) {
    #pragma unroll
    for (int j = 0; j < 8; ++j) {
      const int c = kt * 32 + qd * 8 + j;
      const float v0 = row_s[c * RP + xl];
      const float v1 = row_s[c * RP + xl + 1];
      af[kt][j] = (short)f2bf(xr[kt * 8 + j] + v0 + wx * (v1 - v0));
    }
  }
  __syncthreads();   // row_s dead -> region reusable as a1_s

  // ---- GEMM1: C[64m][128n] = h[64m][128k] * w1[128n][128k]^T (B from global)
  f32x4 acc[8];
  #pragma unroll
  for (int nt = 0; nt < 8; ++nt) acc[nt] = f32x4{0.f, 0.f, 0.f, 0.f};
  #pragma unroll
  for (int nt = 0; nt < 8; ++nt) {
    #pragma unroll
    for (int kt = 0; kt < 4; ++kt) {
      const bf16x8 bf = *(const bf16x8*)&w1bf[(nt * 16 + ln) * 128 + kt * 32 + qd * 8];
      acc[nt] = __builtin_amdgcn_mfma_f32_16x16x32_bf16(af[kt], bf, acc[nt], 0, 0, 0);
    }
  }

  // epilogue: relu(+bias) -> a1_s (bf16). Wave writes only its own 16 rows.
  #pragma unroll
  for (int nt = 0; nt < 8; ++nt) {
    const int n = nt * 16 + ln;
    const float bias = b1[n];
    #pragma unroll
    for (int r = 0; r < 4; ++r) {
      const int m = m0 + qd * 4 + r;
      a1_s[m * PH + n] = f2bf(fmaxf(acc[nt][r] + bias, 0.f));
    }
  }
  // no __syncthreads: each wave reads back only rows it wrote (DS in-order/wave)

  // ---- GEMM2: att[64m][16j] = a1[64m][128k] * w2e[16j][128k]^T
  f32x4 acc2 = f32x4{0.f, 0.f, 0.f, 0.f};
  #pragma unroll
  for (int kt = 0; kt < 4; ++kt) {
    const bf16x8 a2 = *(const bf16x8*)&a1_s[(m0 + ln) * PH + kt * 32 + qd * 8];
    const bf16x8 b2f = *(const bf16x8*)&w2bf[ln * 128 + kt * 32 + qd * 8];
    acc2 = __builtin_amdgcn_mfma_f32_16x16x32_bf16(a2, b2f, acc2, 0, 0, 0);
  }
  const float bias2 = b2[2 * ln];
  #pragma unroll
  for (int r = 0; r < 4; ++r) {
    const int opx = m0 + qd * 4 + r;
    const float v = fmaxf(acc2[r] + bias2, 0.f) + 0.001f;
    att16[((size_t)((b * Hc + y) * Wc) + xg0 + opx) * NA + ln] = f2bf(v);
  }
}

// ---------------------------------------------------------------------------
// K2: block = one image row (192 threads), thread = pixel.
// pb y-interpolated at stage time (batched loads) -> row_s[64][96] f32,
// att from bf16 ws, delta with 4 bins in flight, register bitonic sort.
// ---------------------------------------------------------------------------
__global__ __launch_bounds__(192, 3) void k_bins(
    const float* __restrict__ pb, const unsigned short* __restrict__ att16,
    float* __restrict__ out0, float* __restrict__ out1)
{
  __shared__ __align__(16) float row_s[NB][WI];   // 24576 B

  const int tid = threadIdx.x;      // = xg
  const int y = blockIdx.x;
  const int b = blockIdx.y;

  const float ysf = y * SCL;
  const int y0 = (int)ysf;
  const int y1 = min(y0 + 1, HI - 1);
  const float wy = ysf - (float)y0;

  // ---- batched loads: att (2x bf16x8) + pb rows (16 float4), all in flight
  bf16x8 a16a, a16b;
  {
    const bf16x8* ap = (const bf16x8*)(att16 + ((size_t)((b * Hc + y) * Wc) + tid) * NA);
    a16a = ap[0];
    a16b = ap[1];
  }
  float4 t4a[8], b4a[8];
  #pragma unroll
  for (int i = 0; i < 8; ++i) {
    const int u = tid + 192 * i;          // 0..1535
    const int k = u / 24;
    const int g = u - k * 24;             // float4 group in row
    const float* base = pb + (size_t)(b * NB + k) * (HI * WI);
    t4a[i] = *(const float4*)&base[y0 * WI + g * 4];
    b4a[i] = *(const float4*)&base[y1 * WI + g * 4];
  }

  float am[16];
  #pragma unroll
  for (int j = 0; j < 8; ++j) {
    am[j]     = bf2f((unsigned short)a16a[j]);
    am[8 + j] = bf2f((unsigned short)a16b[j]);
  }

  // ---- consume pb loads: y-interp -> row_s
  #pragma unroll
  for (int i = 0; i < 8; ++i) {
    const int u = tid + 192 * i;
    const int k = u / 24;
    const int g = u - k * 24;
    float4 r;
    r.x = t4a[i].x + wy * (b4a[i].x - t4a[i].x);
    r.y = t4a[i].y + wy * (b4a[i].y - t4a[i].y);
    r.z = t4a[i].z + wy * (b4a[i].z - t4a[i].z);
    r.w = t4a[i].w + wy * (b4a[i].w - t4a[i].w);
    *(float4*)&row_s[k][g * 4] = r;
  }
  __syncthreads();

  const float xsf = tid * SCL;
  const int x0 = (int)xsf;          // <= 94
  const float wx = xsf - (float)x0;

  const size_t obase = (size_t)(b * NB) * (Hc * Wc) + (size_t)y * Wc + tid;
  float v[NB];

  // ---- delta: 4 bins in flight -> 4 independent rcp chains
  #pragma unroll
  for (int kb = 0; kb < NB; kb += 4) {
    float bc[4], dl[4];
    #pragma unroll
    for (int q = 0; q < 4; ++q) {
      const int k = kb + q;
      const float v0 = row_s[k][x0], v1 = row_s[k][x0 + 1];
      bc[q] = v0 + wx * (v1 - v0);
      dl[q] = 0.f;
    }
    #pragma unroll
    for (int j = 0; j < NA; ++j) {
      const float a = am[j];
      #pragma unroll
      for (int q = 0; q < 4; ++q) {
        const float d = a - bc[q];
        const float rq = fmaf(300.f * d, d, 1.f);
        dl[q] = fmaf(d, rcp_fast(rq), dl[q]);
      }
    }
    #pragma unroll
    for (int q = 0; q < 4; ++q) {
      const float bnc = fmaf(dl[q], 1.f / 16.f, bc[q]);
      out0[obase + (size_t)(kb + q) * (Hc * Wc)] = bnc;
      v[kb + q] = fmaf(9.999f, bnc, 0.001f);
    }
  }

  // ---- fully-unrolled bitonic sort on 64 registers (ascending)
  #pragma unroll
  for (int size = 2; size <= NB; size <<= 1) {
    #pragma unroll
    for (int stride = size >> 1; stride >= 1; stride >>= 1) {
      #pragma unroll
      for (int i = 0; i < NB; ++i) {
        if ((i & stride) == 0) {
          const int j = i | stride;
          const bool asc = ((i & size) == 0);
          const float a = v[i], c = v[j];
          const float lo = fminf(a, c), hi = fmaxf(a, c);
          v[i] = asc ? lo : hi;
          v[j] = asc ? hi : lo;
        }
      }
    }
  }

  #pragma unroll
  for (int k = 0; k < NB; ++k) {
    out1[obase + (size_t)k * (Hc * Wc)] = fminf(fmaxf(v[k], 0.001f), 10.0f);
  }
}

// ---------------------------------------------------------------------------
extern "C" void kernel_launch(void* const* d_in, const int* in_sizes, int n_in,
                              void* d_out, int out_size, void* d_ws, size_t ws_size,
                              hipStream_t stream) {
  const float* x   = (const float*)d_in[0];   // (4,128,192,192)
  const float* pb  = (const float*)d_in[1];   // (4,64,96,96)
  const float* pbe = (const float*)d_in[2];   // (4,128,96,96)
  const float* w1  = (const float*)d_in[3];   // (128,128)
  const float* b1  = (const float*)d_in[4];   // (128,)
  const float* w2  = (const float*)d_in[5];   // (32,128)
  const float* b2  = (const float*)d_in[6];   // (32,)

  float* out0 = (float*)d_out;                       // bin_new_centers
  float* out1 = out0 + (size_t)Bc * NB * Hc * Wc;    // bin_centers

  // ws layout: [w1bf 32KB][w2bf 4KB][pad to 64KB][att bf16 4.7MB]
  unsigned short* w1bf = (unsigned short*)d_ws;
  unsigned short* w2bf = w1bf + 16384;
  unsigned short* att16 = (unsigned short*)((char*)d_ws + 65536);  // [b][y][x][j]

  k_prep<<<72, 256, 0, stream>>>(w1, w2, w1bf, w2bf);

  dim3 g1(Wc / 64, Hc, Bc);
  k_att<<<g1, 256, 0, stream>>>(x, pbe, w1bf, b1, w2bf, b2, att16);

  dim3 g2(Hc, Bc);
  k_bins<<<g2, 192, 0, stream>>>(pb, att16, out0, out1);
}